// Round 1
// baseline (320.873 us; speedup 1.0000x reference)
//
#include <hip/hip_runtime.h>
#include <hip/hip_bf16.h>

// ---- problem constants (B=4, T=4096, D=1024, SPAN=128) ----
#define BB 4
#define TT 4096
#define DD 1024
#define SS 128
#define NBLK 32
#define MM (BB*TT)       // 16384 rows

typedef __attribute__((ext_vector_type(8))) short bf16x8;
typedef __attribute__((ext_vector_type(4))) short s16x4;
typedef __attribute__((ext_vector_type(4))) float f32x4;

// counted vmem wait: lets N newest vmem ops stay in flight (in-order retire)
#define VMCNT(N) asm volatile("s_waitcnt vmcnt(" #N ")" ::: "memory")

__device__ __forceinline__ void block_sync() {
    asm volatile("" ::: "memory");
    __builtin_amdgcn_s_barrier();
    asm volatile("" ::: "memory");
}

__device__ __forceinline__ short f2bf(float f) {
    union { float f; unsigned u; } cv; cv.f = f;
    unsigned u = cv.u;
    u += 0x7fffu + ((u >> 16) & 1u);   // RNE
    return (short)(u >> 16);
}

// direct global->LDS DMA, 16B/lane. Contract: LDS dest = wave-uniform
// base + lane*16 (verified for every call site below).
__device__ __forceinline__ void gload16(const short* g, short* l) {
    __builtin_amdgcn_global_load_lds(
        (const __attribute__((address_space(1))) void*)g,
        (__attribute__((address_space(3))) void*)l, 16, 0, 0);
}

// ============================================================
// K0a: x fp32 -> bf16
// ============================================================
__global__ __launch_bounds__(256) void cast_f32_bf16(
    const float* __restrict__ src, short* __restrict__ dst)
{
    const int i = (blockIdx.x * 256 + threadIdx.x) * 4;
    const float4 v = *(const float4*)(src + i);
    s16x4 o;
    o.x = f2bf(v.x); o.y = f2bf(v.y); o.z = f2bf(v.z); o.w = f2bf(v.w);
    *(s16x4*)(dst + i) = o;
}

// K0b: three weight matrices, one launch (dst contiguous [3][1024][1024])
__global__ __launch_bounds__(256) void cast_w3(
    const float* __restrict__ a, const float* __restrict__ b,
    const float* __restrict__ c, short* __restrict__ dst)
{
    const float* src = (blockIdx.y == 0) ? a : (blockIdx.y == 1) ? b : c;
    short* d = dst + (size_t)blockIdx.y * DD * DD;
    const int i = (blockIdx.x * 256 + threadIdx.x) * 4;
    const float4 v = *(const float4*)(src + i);
    s16x4 o;
    o.x = f2bf(v.x); o.y = f2bf(v.y); o.z = f2bf(v.z); o.w = f2bf(v.w);
    *(s16x4*)(d + i) = o;
}

// ============================================================
// K1: fused QKV projection.  Round-5 change: single-buffer 2-barrier
// loop -> depth-1 double buffer with ONE barrier per K-step (stage t+1
// issued right after the barrier, drained by the next __syncthreads).
// Removes a full exposed load-latency per K-step.
// ============================================================
__global__ __launch_bounds__(256) void qkv_gemm(
    const short* __restrict__ X,
    const short* __restrict__ W3,    // [3][1024][1024] bf16
    const float* __restrict__ bq, const float* __restrict__ bk,
    const float* __restrict__ bv,
    short* __restrict__ q, short* __restrict__ k, short* __restrict__ vT)
{
    __shared__ short As[2][4096];    // [buf][128r x 32k]
    __shared__ short Bs[2][4096];

    const int tid = threadIdx.x;
    const int l   = blockIdx.x;
    const int xcd = l & 7;
    const int rr  = l >> 3;            // 0..383
    const int m0  = (xcd * 16 + (rr & 15)) * 128;
    const int n_idx = rr >> 4;         // 0..23
    const int grp = n_idx >> 3;        // 0=Q 1=K 2=V
    const int n0g = (n_idx & 7) * 128;

    const short* W = W3 + (size_t)grp * DD * DD;
    const float* bias = (grp == 0) ? bq : (grp == 1) ? bk : bv;

    const int wv   = tid >> 6, lane = tid & 63;
    const int wm   = wv >> 1,  wn   = wv & 1;
    const int quad = lane >> 4, c16 = lane & 15;
    const int srow = lane >> 2;
    const int scol = (lane & 3) * 8;

    auto stage = [&](int kk) {
        short* as = As[kk & 1];
        short* bs = Bs[kk & 1];
        const int k0 = kk * 32;
#pragma unroll
        for (int s = 0; s < 2; s++) {
            const int row = (wv * 2 + s) * 16 + srow;
            gload16(X + (m0 + row) * DD + k0 + scol, as + row * 32 + scol);
            gload16(W + (n0g + row) * DD + k0 + scol, bs + row * 32 + scol);
        }
    };

    f32x4 acc[4][4];
#pragma unroll
    for (int i = 0; i < 4; i++)
#pragma unroll
        for (int j = 0; j < 4; j++) acc[i][j] = (f32x4){0.f, 0.f, 0.f, 0.f};

    stage(0);

    if (grp != 2) {
        for (int kk = 0; kk < 32; kk++) {
            __syncthreads();                  // drains stage(kk)
            if (kk < 31) stage(kk + 1);       // in flight during compute
            const short* as = As[kk & 1];
            const short* bs = Bs[kk & 1];
            bf16x8 af[4], bfr[4];
#pragma unroll
            for (int i = 0; i < 4; i++)
                af[i] = *(const bf16x8*)(as + (wm * 64 + i * 16 + c16) * 32 + quad * 8);
#pragma unroll
            for (int j = 0; j < 4; j++)
                bfr[j] = *(const bf16x8*)(bs + (wn * 64 + j * 16 + c16) * 32 + quad * 8);
#pragma unroll
            for (int i = 0; i < 4; i++)
#pragma unroll
                for (int j = 0; j < 4; j++)
                    acc[i][j] = __builtin_amdgcn_mfma_f32_16x16x32_bf16(af[i], bfr[j], acc[i][j], 0, 0, 0);
        }
        short* Y = (grp == 0) ? q : k;
#pragma unroll
        for (int j = 0; j < 4; j++) {
            const int col = n0g + wn * 64 + j * 16 + c16;
            const float bc = bias[col];
#pragma unroll
            for (int i = 0; i < 4; i++) {
                const int row = m0 + wm * 64 + i * 16 + quad * 4;
#pragma unroll
                for (int r = 0; r < 4; r++)
                    Y[(row + r) * DD + col] = f2bf(acc[i][j][r] + bc);
            }
        }
    } else {
        for (int kk = 0; kk < 32; kk++) {
            __syncthreads();
            if (kk < 31) stage(kk + 1);
            const short* as = As[kk & 1];
            const short* bs = Bs[kk & 1];
            bf16x8 af[4], bfr[4];
#pragma unroll
            for (int i = 0; i < 4; i++)
                af[i] = *(const bf16x8*)(as + (wm * 64 + i * 16 + c16) * 32 + quad * 8);
#pragma unroll
            for (int j = 0; j < 4; j++)
                bfr[j] = *(const bf16x8*)(bs + (wn * 64 + j * 16 + c16) * 32 + quad * 8);
#pragma unroll
            for (int i = 0; i < 4; i++)
#pragma unroll
                for (int j = 0; j < 4; j++)
                    acc[i][j] = __builtin_amdgcn_mfma_f32_16x16x32_bf16(bfr[j], af[i], acc[i][j], 0, 0, 0);
        }
        const int b  = m0 >> 12;
        const int t0 = m0 & 4095;
#pragma unroll
        for (int j = 0; j < 4; j++) {
#pragma unroll
            for (int r = 0; r < 4; r++) {
                const int drow = n0g + wn * 64 + j * 16 + quad * 4 + r;
                const float bc = bias[drow];
#pragma unroll
                for (int i = 0; i < 4; i++) {
                    const int tcol = t0 + wm * 64 + i * 16 + c16;
                    vT[(b * DD + drow) * TT + tcol] = f2bf(acc[i][j][r] + bc);
                }
            }
        }
    }
}

// ============================================================
// K2: fused windowed attention per (b, n, qh).  Round-5 change:
// depth-2 prefetch with counted vmcnt + raw s_barrier in BOTH phases
// (3 rotating buffers each).  1 block/CU -> all latency hiding is
// intra-block; depth-1's vmcnt(0)-drain-per-step was the MLP killer.
//
// LDS map (shorts):
//   phase 1: buf i at i*20480: Q[2][64][32]@+0, K[2][256][32]@+4096  (3 bufs)
//   P      : @61440, per-wave [16][264]                (bytes 122880..156671)
//   phase 2: V bufs [4][128][32] at i*16384, i=0..2    (bytes 0..98303)
//
// vmcnt accounting (per lane, in-order retirement):
//   phase-1 stage = 10 loads; steady wait = vmcnt(10) (next stage in flight)
//   phase-2 stage = 8 loads; odd steps add 32 O-stores issued AFTER the
//   current stage -> newest-ops bound = 8+32 = 40 for s in [2,14];
//   s<2: only next stage (8); s=15: drain.
// ============================================================
__global__ __launch_bounds__(256) void attn_fused(
    const short* __restrict__ Q,
    const short* __restrict__ Kb,
    const short* __restrict__ VT,    // [B,1024,4096]
    float* __restrict__ O)           // [16384,1024] fp32
{
    __shared__ short lds[78336];     // 153 KB

    const int l   = blockIdx.x;
    const int xcd = l & 7;
    const int rr  = l >> 3;               // 0..31
    const int n   = xcd * 4 + (rr & 3);   // both qh of one (b,n) on same XCD
    const int qh  = (rr >> 2) & 1;
    const int b   = rr >> 3;

    const int tid  = threadIdx.x;
    const int wv   = tid >> 6, lane = tid & 63;
    const int quad = lane >> 4, c16 = lane & 15;
    const int srow = tid >> 2;            // 0..63
    const int scol = (tid & 3) * 8;

    const int qrow   = b * TT + n * SS + qh * 64;
    const int krow   = b * TT + n * SS - SS;
    const int bstart = b * TT;

    // ---------------- phase 1: S = Q.K^T, BK=64, depth-2 ----------------
    f32x4 acc[16];
#pragma unroll
    for (int j = 0; j < 16; j++) acc[j] = (f32x4){0.f, 0.f, 0.f, 0.f};

    auto stage1 = [&](int kk, int bi) {
        short* qb   = lds + bi * 20480;
        short* kbuf = qb + 4096;
        const int k0 = kk * 64;
#pragma unroll
        for (int ks = 0; ks < 2; ks++) {
            gload16(Q + (qrow + srow) * DD + k0 + ks * 32 + scol,
                    qb + ks * 2048 + srow * 32 + scol);
#pragma unroll
            for (int s = 0; s < 4; s++) {
                const int row = srow + s * 64;
                int g = krow + row;
                if (g < bstart) g = bstart;   // n==0 pad rows (masked below)
                gload16(Kb + g * DD + k0 + ks * 32 + scol,
                        kbuf + ks * 8192 + row * 32 + scol);
            }
        }
    };

    stage1(0, 0);
    stage1(1, 1);
    for (int kk = 0; kk < 16; kk++) {
        if (kk < 15) { VMCNT(10); } else { VMCNT(0); }   // own stage(kk) landed
        block_sync();                                     // everyone's landed
        if (kk < 14) stage1(kk + 2, (kk + 2) % 3);        // 2 tiles in flight
        const short* qb   = lds + (kk % 3) * 20480;
        const short* kbuf = qb + 4096;
#pragma unroll
        for (int ks = 0; ks < 2; ks++) {
            bf16x8 a = *(const bf16x8*)(qb + ks * 2048 + (wv * 16 + c16) * 32 + quad * 8);
#pragma unroll
            for (int j = 0; j < 16; j++) {
                bf16x8 bf = *(const bf16x8*)(kbuf + ks * 8192 + (j * 16 + c16) * 32 + quad * 8);
                acc[j] = __builtin_amdgcn_mfma_f32_16x16x32_bf16(a, bf, acc[j], 0, 0, 0);
            }
        }
    }

    __syncthreads();            // all waves done reading phase-1 LDS region

    // ---- phase-2 prologue issued BEFORE softmax: V loads fly under it ----
    const int tbase = n * SS - SS;
    auto stage2 = [&](int s, short* vbuf) {
        const int d0 = (s >> 1) * 128;
        const int kh = (s & 1) * 128;
#pragma unroll
        for (int kc = 0; kc < 4; kc++) {
#pragma unroll
            for (int s64 = 0; s64 < 2; s64++) {
                const int row = srow + s64 * 64;     // d-local 0..127
                int t = tbase + kh + kc * 32 + scol;
                if (t < 0) t = 0;                    // n==0 pad keys: P==0 there
                gload16(VT + (size_t)(b * DD + d0 + row) * TT + t,
                        vbuf + kc * 4096 + row * 32 + scol);
            }
        }
    };
    stage2(0, lds);
    stage2(1, lds + 16384);

    // ---------------- softmax + P -> LDS (A-frag layout) ----------------
    short* Pw = lds + 61440 + wv * (16 * 264);
    const float scale = 0.03125f;   // 1/sqrt(1024)
#pragma unroll
    for (int r = 0; r < 4; r++) {
        const int q_idx = qh * 64 + wv * 16 + quad * 4 + r;   // 0..127
        float mx = -3.0e38f;
#pragma unroll
        for (int j = 0; j < 16; j++) {
            const int k_idx = j * 16 + c16;                    // 0..255
            const int rel = k_idx - SS - q_idx;
            const bool valid = (rel <= 0) & (rel > -SS) & ((n > 0) | (k_idx >= SS));
            const float sv = valid ? acc[j][r] * scale : -3.0e38f;
            acc[j][r] = sv;
            mx = fmaxf(mx, sv);
        }
#pragma unroll
        for (int o = 1; o < 16; o <<= 1) mx = fmaxf(mx, __shfl_xor(mx, o));
        float sm = 0.f;
#pragma unroll
        for (int j = 0; j < 16; j++) {
            const float p = __expf(acc[j][r] - mx);
            acc[j][r] = p;
            sm += p;
        }
#pragma unroll
        for (int o = 1; o < 16; o <<= 1) sm += __shfl_xor(sm, o);
        const float inv = 1.0f / sm;
#pragma unroll
        for (int j = 0; j < 16; j++)
            Pw[(quad * 4 + r) * 264 + j * 16 + c16] = f2bf(acc[j][r] * inv);
    }

    // ---------------- phase 2: O = P.V, depth-2 over (d0, k-half) ----------------
    f32x4 o8[8];
#pragma unroll
    for (int j = 0; j < 8; j++) o8[j] = (f32x4){0.f, 0.f, 0.f, 0.f};

    for (int s = 0; s < 16; s++) {
        if (s < 2)       { VMCNT(8); }     // only stage(s+1) newer than stage(s)
        else if (s < 15) { VMCNT(40); }    // stage(s+1)=8 + one store batch=32
        else             { VMCNT(0); }
        block_sync();
        if (s < 14) stage2(s + 2, lds + ((s + 2) % 3) * 16384);
        const short* vbuf = lds + (s % 3) * 16384;
        const int kh = (s & 1) * 128;
#pragma unroll
        for (int kc = 0; kc < 4; kc++) {
            bf16x8 a = *(const bf16x8*)(Pw + c16 * 264 + kh + kc * 32 + quad * 8);
#pragma unroll
            for (int jj = 0; jj < 8; jj++) {
                bf16x8 bf = *(const bf16x8*)(vbuf + kc * 4096 + (jj * 16 + c16) * 32 + quad * 8);
                o8[jj] = __builtin_amdgcn_mfma_f32_16x16x32_bf16(a, bf, o8[jj], 0, 0, 0);
            }
        }
        if (s & 1) {
            const int d0 = (s >> 1) * 128;
#pragma unroll
            for (int jj = 0; jj < 8; jj++) {
#pragma unroll
                for (int r = 0; r < 4; r++)
                    O[(size_t)(qrow + wv * 16 + quad * 4 + r) * DD + d0 + jj * 16 + c16] = o8[jj][r];
                o8[jj] = (f32x4){0.f, 0.f, 0.f, 0.f};
            }
        }
    }
}

// ============================================================
extern "C" void kernel_launch(void* const* d_in, const int* in_sizes, int n_in,
                              void* d_out, int out_size, void* d_ws, size_t ws_size,
                              hipStream_t stream) {
    const float* x  = (const float*)d_in[0];
    const float* Wq = (const float*)d_in[1];
    const float* bq = (const float*)d_in[2];
    const float* Wk = (const float*)d_in[3];
    const float* bk = (const float*)d_in[4];
    const float* Wv = (const float*)d_in[5];
    const float* bv = (const float*)d_in[6];
    float* out = (float*)d_out;

    char* ws = (char*)d_ws;
    const size_t SZ = (size_t)MM * DD * 2;     // 33,554,432 B
    short* q   = (short*)(ws);
    short* k   = (short*)(ws + SZ);
    short* vT  = (short*)(ws + 2 * SZ);
    short* xb  = (short*)(ws + 3 * SZ);
    short* w3b = (short*)(ws + 4 * SZ);        // [3][1024][1024] contiguous

    dim3 blk(256);
    cast_f32_bf16<<<MM * DD / 1024, blk, 0, stream>>>(x, xb);
    cast_w3<<<dim3(DD * DD / 1024, 3), blk, 0, stream>>>(Wq, Wk, Wv, w3b);

    qkv_gemm<<<3072, blk, 0, stream>>>(xb, w3b, bq, bk, bv, q, k, vT);

    attn_fused<<<256, blk, 0, stream>>>(q, k, vT, out);
}

// Round 3
// 300.212 us; speedup vs baseline: 1.0688x; 1.0688x over previous
//
#include <hip/hip_runtime.h>
#include <hip/hip_bf16.h>

// ---- problem constants (B=4, T=4096, D=1024, SPAN=128) ----
#define BB 4
#define TT 4096
#define DD 1024
#define SS 128
#define MM (BB*TT)       // 16384 rows

typedef __attribute__((ext_vector_type(8))) short bf16x8;
typedef __attribute__((ext_vector_type(4))) short s16x4;
typedef __attribute__((ext_vector_type(4))) float f32x4;

// counted vmem wait: lets N newest vmem ops stay in flight (in-order retire)
#define VMCNT(N) asm volatile("s_waitcnt vmcnt(" #N ")" ::: "memory")
#define LGKM0()  asm volatile("s_waitcnt lgkmcnt(0)" ::: "memory")

__device__ __forceinline__ void block_sync() {
    asm volatile("" ::: "memory");
    __builtin_amdgcn_s_barrier();
    asm volatile("" ::: "memory");
}

__device__ __forceinline__ short f2bf(float f) {
    union { float f; unsigned u; } cv; cv.f = f;
    unsigned u = cv.u;
    u += 0x7fffu + ((u >> 16) & 1u);   // RNE
    return (short)(u >> 16);
}

// direct global->LDS DMA, 16B/lane. Contract: LDS dest = wave-uniform
// base + lane*16 (verified for every call site below).
__device__ __forceinline__ void gload16(const short* g, short* l) {
    __builtin_amdgcn_global_load_lds(
        (const __attribute__((address_space(1))) void*)g,
        (__attribute__((address_space(3))) void*)l, 16, 0, 0);
}

// ============================================================
// K0a: x fp32 -> bf16
// ============================================================
__global__ __launch_bounds__(256) void cast_f32_bf16(
    const float* __restrict__ src, short* __restrict__ dst)
{
    const int i = (blockIdx.x * 256 + threadIdx.x) * 4;
    const float4 v = *(const float4*)(src + i);
    s16x4 o;
    o.x = f2bf(v.x); o.y = f2bf(v.y); o.z = f2bf(v.z); o.w = f2bf(v.w);
    *(s16x4*)(dst + i) = o;
}

// K0b: three weight matrices, one launch (dst contiguous [3][1024][1024])
__global__ __launch_bounds__(256) void cast_w3(
    const float* __restrict__ a, const float* __restrict__ b,
    const float* __restrict__ c, short* __restrict__ dst)
{
    const float* src = (blockIdx.y == 0) ? a : (blockIdx.y == 1) ? b : c;
    short* d = dst + (size_t)blockIdx.y * DD * DD;
    const int i = (blockIdx.x * 256 + threadIdx.x) * 4;
    const float4 v = *(const float4*)(src + i);
    s16x4 o;
    o.x = f2bf(v.x); o.y = f2bf(v.y); o.z = f2bf(v.z); o.w = f2bf(v.w);
    *(s16x4*)(d + i) = o;
}

// ============================================================
// K1 (round-3 rewrite): 256x256 8-phase GEMM (m201 template, plain HIP).
// BK=64, 512 thr / 8 waves (2M x 4N), per-wave tile 128x64, LDS 128 KiB
// (2 dbuf x 2 half x {A,B} x 128x64 bf16).  One half-tile stage per
// phase; counted VMCNT(4) only at phase-4/8 boundaries (2 half-tiles
// stay in flight across barriers); T2 XOR-swizzle slot^=(row&7)
// (linear DMA dest + inverse-swizzled GLOBAL source + swizzled read);
// T5 setprio around each 16-MFMA cluster.
//
// Steady-state stage schedule for iter computing (t0=2i, t1=2i+1):
//   p0: A0(t1)->buf1   p1: A1(t1)->buf1   p2: B0(t0+2)->buf0
//   p3: B1(t0+2)->buf0 [VMCNT(4)]         p4: A0(t0+2)->buf0
//   p5: A1(t0+2)->buf0 p6: B0(t1+2)->buf1 p7: B1(t1+2)->buf1 [VMCNT(4)]
// Region-free and landing guarantees verified for every edge incl.
// prologue {A(0),B(0),B(1); VMCNT(4)} and tail (it==7 -> VMCNT(0)).
// ============================================================

#define MF(a_, b_, c_) ((GRP == 2)                                            \
    ? __builtin_amdgcn_mfma_f32_16x16x32_bf16((b_), (a_), (c_), 0, 0, 0)      \
    : __builtin_amdgcn_mfma_f32_16x16x32_bf16((a_), (b_), (c_), 0, 0, 0))

#define QKV_PHASE(ABASE, P, STAGE_STMT, VM_STMT)                              \
  do {                                                                        \
    bf16x8 af0k0 = *(const bf16x8*)((ABASE) + (((P)*2)*16   + c16) * 64 + sw0);\
    bf16x8 af0k1 = *(const bf16x8*)((ABASE) + (((P)*2)*16   + c16) * 64 + sw1);\
    bf16x8 af1k0 = *(const bf16x8*)((ABASE) + (((P)*2+1)*16 + c16) * 64 + sw0);\
    bf16x8 af1k1 = *(const bf16x8*)((ABASE) + (((P)*2+1)*16 + c16) * 64 + sw1);\
    STAGE_STMT;                                                               \
    block_sync();                                                             \
    LGKM0();                                                                  \
    __builtin_amdgcn_s_setprio(1);                                            \
    _Pragma("unroll")                                                         \
    for (int nj = 0; nj < 4; nj++) {                                          \
      acc[(P)*2][nj]   = MF(af0k0, bf[nj][0], acc[(P)*2][nj]);                \
      acc[(P)*2][nj]   = MF(af0k1, bf[nj][1], acc[(P)*2][nj]);                \
      acc[(P)*2+1][nj] = MF(af1k0, bf[nj][0], acc[(P)*2+1][nj]);              \
      acc[(P)*2+1][nj] = MF(af1k1, bf[nj][1], acc[(P)*2+1][nj]);              \
    }                                                                         \
    __builtin_amdgcn_s_setprio(0);                                            \
    VM_STMT;                                                                  \
    block_sync();                                                             \
  } while (0)

template<int GRP>
__device__ __forceinline__ void qkv_core(
    const short* __restrict__ X, const short* __restrict__ W,
    const float* __restrict__ bias,
    short* __restrict__ Y, short* __restrict__ vT,
    short* lds, const int m_base, const int n_base)
{
    const int tid  = threadIdx.x;
    const int wv   = tid >> 6, lane = tid & 63;
    const int wm   = wv >> 2,  wn   = wv & 3;
    const int quad = lane >> 4, c16 = lane & 15;
    const int swz  = c16 & 7;
    const int sw0  = ((quad)     ^ swz) * 8;   // kk=0 logical slot quad
    const int sw1  = ((quad + 4) ^ swz) * 8;   // kk=1 logical slot quad+4

    // one half-tile = 128 rows x 64 k bf16 = 16 KiB = 2 gload16/thread.
    auto stageA = [&](int k0, int d, int h) {
        short* dst = lds + d * 16384 + h * 8192;
#pragma unroll
        for (int g = 0; g < 2; g++) {
            const int idx = g * 512 + tid;
            const int row = idx >> 3, slot = idx & 7;
            gload16(X + (size_t)(m_base + h * 128 + row) * DD + k0
                      + ((slot ^ (row & 7)) * 8),
                    dst + row * 64 + slot * 8);
        }
    };
    auto stageB = [&](int k0, int d, int h) {
        short* dst = lds + 32768 + d * 16384 + h * 8192;
#pragma unroll
        for (int g = 0; g < 2; g++) {
            const int idx = g * 512 + tid;
            const int row = idx >> 3, slot = idx & 7;
            gload16(W + (size_t)(n_base + h * 128 + row) * DD + k0
                      + ((slot ^ (row & 7)) * 8),
                    dst + row * 64 + slot * 8);
        }
    };

    f32x4 acc[8][4];
#pragma unroll
    for (int i = 0; i < 8; i++)
#pragma unroll
        for (int j = 0; j < 4; j++) acc[i][j] = (f32x4){0.f, 0.f, 0.f, 0.f};

    // prologue: tile0 A+B, tile1 B  (6 half-stages = 12 loads/lane)
    stageA(0, 0, 0);  stageA(0, 0, 1);
    stageB(0, 0, 0);  stageB(0, 0, 1);
    stageB(64, 1, 0); stageB(64, 1, 1);
    VMCNT(4);                       // tile0 landed; B(1) halves in flight
    block_sync();

    const short* Abuf0 = lds + wm * 8192;
    const short* Abuf1 = lds + 16384 + wm * 8192;
    const short* Bbuf0 = lds + 32768 + (wn >> 1) * 8192 + (wn & 1) * 4096;
    const short* Bbuf1 = lds + 49152 + (wn >> 1) * 8192 + (wn & 1) * 4096;

    bf16x8 bf[4][2];

    for (int it = 0; it < 8; ++it) {
        const int k1 = it * 128 + 64;     // K-tile t1
        const int k2 = it * 128 + 128;    // K-tile t0+2
        const int k3 = it * 128 + 192;    // K-tile t1+2
        const bool more = (it < 7);

#pragma unroll
        for (int nj = 0; nj < 4; nj++) {
            bf[nj][0] = *(const bf16x8*)(Bbuf0 + (nj * 16 + c16) * 64 + sw0);
            bf[nj][1] = *(const bf16x8*)(Bbuf0 + (nj * 16 + c16) * 64 + sw1);
        }
        QKV_PHASE(Abuf0, 0, stageA(k1, 1, 0), ((void)0));
        QKV_PHASE(Abuf0, 1, stageA(k1, 1, 1), ((void)0));
        QKV_PHASE(Abuf0, 2, if (more) stageB(k2, 0, 0), ((void)0));
        QKV_PHASE(Abuf0, 3, if (more) stageB(k2, 0, 1),
                  if (more) { VMCNT(4); } else { VMCNT(0); });

#pragma unroll
        for (int nj = 0; nj < 4; nj++) {
            bf[nj][0] = *(const bf16x8*)(Bbuf1 + (nj * 16 + c16) * 64 + sw0);
            bf[nj][1] = *(const bf16x8*)(Bbuf1 + (nj * 16 + c16) * 64 + sw1);
        }
        QKV_PHASE(Abuf1, 0, if (more) stageA(k2, 0, 0), ((void)0));
        QKV_PHASE(Abuf1, 1, if (more) stageA(k2, 0, 1), ((void)0));
        QKV_PHASE(Abuf1, 2, if (more) stageB(k3, 1, 0), ((void)0));
        QKV_PHASE(Abuf1, 3, if (more) stageB(k3, 1, 1),
                  if (more) { VMCNT(4); } else { VMCNT(0); });
    }

    // ---- epilogue ----
    if (GRP != 2) {
#pragma unroll
        for (int nj = 0; nj < 4; nj++) {
            const int col = n_base + wn * 64 + nj * 16 + c16;
            const float bc = bias[col];
#pragma unroll
            for (int mi = 0; mi < 8; mi++) {
                const int row = m_base + wm * 128 + mi * 16 + quad * 4;
#pragma unroll
                for (int r = 0; r < 4; r++)
                    Y[(size_t)(row + r) * DD + col] = f2bf(acc[mi][nj][r] + bc);
            }
        }
    } else {
        // operand-swapped: acc = C^T, store to vT [B,1024,4096] coalesced-ish
#pragma unroll
        for (int nj = 0; nj < 4; nj++) {
#pragma unroll
            for (int r = 0; r < 4; r++) {
                const int drow = n_base + wn * 64 + nj * 16 + quad * 4 + r;
                const float bc = bias[drow];
#pragma unroll
                for (int mi = 0; mi < 8; mi++) {
                    const int mcol = m_base + wm * 128 + mi * 16 + c16;
                    vT[((size_t)(mcol >> 12) * DD + drow) * TT + (mcol & 4095)]
                        = f2bf(acc[mi][nj][r] + bc);
                }
            }
        }
    }
}

__global__ __launch_bounds__(512, 2) void qkv_gemm8(
    const short* __restrict__ X, const short* __restrict__ W3,
    const float* __restrict__ bq, const float* __restrict__ bk,
    const float* __restrict__ bv,
    short* __restrict__ q, short* __restrict__ k, short* __restrict__ vT)
{
    __shared__ __align__(16) short lds[65536];   // 128 KiB
    const int bid = blockIdx.x;                  // 768 blocks
    const int wg  = (bid & 7) * 96 + (bid >> 3); // bijective XCD swizzle
    const int mt  = wg & 63;                     // 0..63
    const int cn  = wg >> 6;                     // 0..11
    const int grp = cn >> 2;                     // 0=Q 1=K 2=V
    const int nt  = cn & 3;                      // 0..3
    const int m_base = mt * 256;
    const int n_base = nt * 256;
    if (grp == 0)      qkv_core<0>(X, W3,              bq, q, nullptr, lds, m_base, n_base);
    else if (grp == 1) qkv_core<1>(X, W3 + DD * DD,    bk, k, nullptr, lds, m_base, n_base);
    else               qkv_core<2>(X, W3 + 2 * DD * DD, bv, nullptr, vT, lds, m_base, n_base);
}

// ============================================================
// K2: fused windowed attention — REVERTED verbatim to the round-1
// kernel (passed, ~143 us).  Attn restructuring resumes next round,
// one structural change at a time.
// ============================================================
__global__ __launch_bounds__(256) void attn_fused(
    const short* __restrict__ Q,
    const short* __restrict__ Kb,
    const short* __restrict__ VT,    // [B,1024,4096]
    float* __restrict__ O)           // [16384,1024] fp32
{
    __shared__ short lds[78336];     // 153 KB

    const int l   = blockIdx.x;
    const int xcd = l & 7;
    const int rr  = l >> 3;               // 0..31
    const int n   = xcd * 4 + (rr & 3);   // both qh of one (b,n) on same XCD
    const int qh  = (rr >> 2) & 1;
    const int b   = rr >> 3;

    const int tid  = threadIdx.x;
    const int wv   = tid >> 6, lane = tid & 63;
    const int quad = lane >> 4, c16 = lane & 15;
    const int srow = tid >> 2;            // 0..63
    const int scol = (tid & 3) * 8;

    const int qrow   = b * TT + n * SS + qh * 64;
    const int krow   = b * TT + n * SS - SS;
    const int bstart = b * TT;

    // ---------------- phase 1: S = Q.K^T, BK=64, depth-2 ----------------
    f32x4 acc[16];
#pragma unroll
    for (int j = 0; j < 16; j++) acc[j] = (f32x4){0.f, 0.f, 0.f, 0.f};

    auto stage1 = [&](int kk, int bi) {
        short* qb   = lds + bi * 20480;
        short* kbuf = qb + 4096;
        const int k0 = kk * 64;
#pragma unroll
        for (int ks = 0; ks < 2; ks++) {
            gload16(Q + (qrow + srow) * DD + k0 + ks * 32 + scol,
                    qb + ks * 2048 + srow * 32 + scol);
#pragma unroll
            for (int s = 0; s < 4; s++) {
                const int row = srow + s * 64;
                int g = krow + row;
                if (g < bstart) g = bstart;   // n==0 pad rows (masked below)
                gload16(Kb + g * DD + k0 + ks * 32 + scol,
                        kbuf + ks * 8192 + row * 32 + scol);
            }
        }
    };

    stage1(0, 0);
    stage1(1, 1);
    for (int kk = 0; kk < 16; kk++) {
        if (kk < 15) { VMCNT(10); } else { VMCNT(0); }   // own stage(kk) landed
        block_sync();                                     // everyone's landed
        if (kk < 14) stage1(kk + 2, (kk + 2) % 3);        // 2 tiles in flight
        const short* qb   = lds + (kk % 3) * 20480;
        const short* kbuf = qb + 4096;
#pragma unroll
        for (int ks = 0; ks < 2; ks++) {
            bf16x8 a = *(const bf16x8*)(qb + ks * 2048 + (wv * 16 + c16) * 32 + quad * 8);
#pragma unroll
            for (int j = 0; j < 16; j++) {
                bf16x8 bf = *(const bf16x8*)(kbuf + ks * 8192 + (j * 16 + c16) * 32 + quad * 8);
                acc[j] = __builtin_amdgcn_mfma_f32_16x16x32_bf16(a, bf, acc[j], 0, 0, 0);
            }
        }
    }

    __syncthreads();            // all waves done reading phase-1 LDS region

    // ---- phase-2 prologue issued BEFORE softmax: V loads fly under it ----
    const int tbase = n * SS - SS;
    auto stage2 = [&](int s, short* vbuf) {
        const int d0 = (s >> 1) * 128;
        const int kh = (s & 1) * 128;
#pragma unroll
        for (int kc = 0; kc < 4; kc++) {
#pragma unroll
            for (int s64 = 0; s64 < 2; s64++) {
                const int row = srow + s64 * 64;     // d-local 0..127
                int t = tbase + kh + kc * 32 + scol;
                if (t < 0) t = 0;                    // n==0 pad keys: P==0 there
                gload16(VT + (size_t)(b * DD + d0 + row) * TT + t,
                        vbuf + kc * 4096 + row * 32 + scol);
            }
        }
    };
    stage2(0, lds);
    stage2(1, lds + 16384);

    // ---------------- softmax + P -> LDS (A-frag layout) ----------------
    short* Pw = lds + 61440 + wv * (16 * 264);
    const float scale = 0.03125f;   // 1/sqrt(1024)
#pragma unroll
    for (int r = 0; r < 4; r++) {
        const int q_idx = qh * 64 + wv * 16 + quad * 4 + r;   // 0..127
        float mx = -3.0e38f;
#pragma unroll
        for (int j = 0; j < 16; j++) {
            const int k_idx = j * 16 + c16;                    // 0..255
            const int rel = k_idx - SS - q_idx;
            const bool valid = (rel <= 0) & (rel > -SS) & ((n > 0) | (k_idx >= SS));
            const float sv = valid ? acc[j][r] * scale : -3.0e38f;
            acc[j][r] = sv;
            mx = fmaxf(mx, sv);
        }
#pragma unroll
        for (int o = 1; o < 16; o <<= 1) mx = fmaxf(mx, __shfl_xor(mx, o));
        float sm = 0.f;
#pragma unroll
        for (int j = 0; j < 16; j++) {
            const float p = __expf(acc[j][r] - mx);
            acc[j][r] = p;
            sm += p;
        }
#pragma unroll
        for (int o = 1; o < 16; o <<= 1) sm += __shfl_xor(sm, o);
        const float inv = 1.0f / sm;
#pragma unroll
        for (int j = 0; j < 16; j++)
            Pw[(quad * 4 + r) * 264 + j * 16 + c16] = f2bf(acc[j][r] * inv);
    }

    // ---------------- phase 2: O = P.V, depth-2 over (d0, k-half) ----------------
    f32x4 o8[8];
#pragma unroll
    for (int j = 0; j < 8; j++) o8[j] = (f32x4){0.f, 0.f, 0.f, 0.f};

    for (int s = 0; s < 16; s++) {
        if (s < 2)       { VMCNT(8); }     // only stage(s+1) newer than stage(s)
        else if (s < 15) { VMCNT(40); }    // stage(s+1)=8 + one store batch=32
        else             { VMCNT(16); }    // stores(13) issued after stage(15)
        block_sync();
        if (s < 14) stage2(s + 2, lds + ((s + 2) % 3) * 16384);
        const short* vbuf = lds + (s % 3) * 16384;
        const int kh = (s & 1) * 128;
#pragma unroll
        for (int kc = 0; kc < 4; kc++) {
            bf16x8 a = *(const bf16x8*)(Pw + c16 * 264 + kh + kc * 32 + quad * 8);
#pragma unroll
            for (int jj = 0; jj < 8; jj++) {
                bf16x8 bf = *(const bf16x8*)(vbuf + kc * 4096 + (jj * 16 + c16) * 32 + quad * 8);
                o8[jj] = __builtin_amdgcn_mfma_f32_16x16x32_bf16(a, bf, o8[jj], 0, 0, 0);
            }
        }
        if (s & 1) {
            const int d0 = (s >> 1) * 128;
#pragma unroll
            for (int jj = 0; jj < 8; jj++) {
#pragma unroll
                for (int r = 0; r < 4; r++)
                    O[(size_t)(qrow + wv * 16 + quad * 4 + r) * DD + d0 + jj * 16 + c16] = o8[jj][r];
                o8[jj] = (f32x4){0.f, 0.f, 0.f, 0.f};
            }
        }
    }
}

// ============================================================
extern "C" void kernel_launch(void* const* d_in, const int* in_sizes, int n_in,
                              void* d_out, int out_size, void* d_ws, size_t ws_size,
                              hipStream_t stream) {
    const float* x  = (const float*)d_in[0];
    const float* Wq = (const float*)d_in[1];
    const float* bq = (const float*)d_in[2];
    const float* Wk = (const float*)d_in[3];
    const float* bk = (const float*)d_in[4];
    const float* Wv = (const float*)d_in[5];
    const float* bv = (const float*)d_in[6];
    float* out = (float*)d_out;

    char* ws = (char*)d_ws;
    const size_t SZ = (size_t)MM * DD * 2;     // 33,554,432 B
    short* q   = (short*)(ws);
    short* k   = (short*)(ws + SZ);
    short* vT  = (short*)(ws + 2 * SZ);
    short* xb  = (short*)(ws + 3 * SZ);
    short* w3b = (short*)(ws + 4 * SZ);        // [3][1024][1024] contiguous

    dim3 blk(256);
    cast_f32_bf16<<<MM * DD / 1024, blk, 0, stream>>>(x, xb);
    cast_w3<<<dim3(DD * DD / 1024, 3), blk, 0, stream>>>(Wq, Wk, Wv, w3b);

    qkv_gemm8<<<768, 512, 0, stream>>>(xb, w3b, bq, bk, bv, q, k, vT);

    attn_fused<<<256, 256, 0, stream>>>(q, k, vT, out);
}

// Round 5
// 295.577 us; speedup vs baseline: 1.0856x; 1.0157x over previous
//
#include <hip/hip_runtime.h>
#include <hip/hip_bf16.h>

// ---- problem constants (B=4, T=4096, D=1024, SPAN=128) ----
#define BB 4
#define TT 4096
#define DD 1024
#define SS 128
#define MM (BB*TT)       // 16384 rows

typedef __attribute__((ext_vector_type(8))) short bf16x8;
typedef __attribute__((ext_vector_type(4))) short s16x4;
typedef __attribute__((ext_vector_type(4))) float f32x4;

// counted vmem wait: lets N newest vmem ops stay in flight (in-order retire)
#define VMCNT(N) asm volatile("s_waitcnt vmcnt(" #N ")" ::: "memory")
#define LGKM0()  asm volatile("s_waitcnt lgkmcnt(0)" ::: "memory")

__device__ __forceinline__ void block_sync() {
    asm volatile("" ::: "memory");
    __builtin_amdgcn_s_barrier();
    asm volatile("" ::: "memory");
}

__device__ __forceinline__ short f2bf(float f) {
    union { float f; unsigned u; } cv; cv.f = f;
    unsigned u = cv.u;
    u += 0x7fffu + ((u >> 16) & 1u);   // RNE
    return (short)(u >> 16);
}

// direct global->LDS DMA, 16B/lane. Contract: LDS dest = wave-uniform
// base + lane*16 (verified for every call site below).
__device__ __forceinline__ void gload16(const short* g, short* l) {
    __builtin_amdgcn_global_load_lds(
        (const __attribute__((address_space(1))) void*)g,
        (__attribute__((address_space(3))) void*)l, 16, 0, 0);
}

// ============================================================
// K0a: x fp32 -> bf16
// ============================================================
__global__ __launch_bounds__(256) void cast_f32_bf16(
    const float* __restrict__ src, short* __restrict__ dst)
{
    const int i = (blockIdx.x * 256 + threadIdx.x) * 4;
    const float4 v = *(const float4*)(src + i);
    s16x4 o;
    o.x = f2bf(v.x); o.y = f2bf(v.y); o.z = f2bf(v.z); o.w = f2bf(v.w);
    *(s16x4*)(dst + i) = o;
}

// K0b: three weight matrices, one launch (dst contiguous [3][1024][1024])
__global__ __launch_bounds__(256) void cast_w3(
    const float* __restrict__ a, const float* __restrict__ b,
    const float* __restrict__ c, short* __restrict__ dst)
{
    const float* src = (blockIdx.y == 0) ? a : (blockIdx.y == 1) ? b : c;
    short* d = dst + (size_t)blockIdx.y * DD * DD;
    const int i = (blockIdx.x * 256 + threadIdx.x) * 4;
    const float4 v = *(const float4*)(src + i);
    s16x4 o;
    o.x = f2bf(v.x); o.y = f2bf(v.y); o.z = f2bf(v.z); o.w = f2bf(v.w);
    *(s16x4*)(d + i) = o;
}

// ============================================================
// K1: 256x256 8-phase GEMM — UNCHANGED from round 3 (verified, ~131 us,
// ~93% of the measured K=1024 8-phase structure ceiling; control).
// ============================================================

#define MF(a_, b_, c_) ((GRP == 2)                                            \
    ? __builtin_amdgcn_mfma_f32_16x16x32_bf16((b_), (a_), (c_), 0, 0, 0)      \
    : __builtin_amdgcn_mfma_f32_16x16x32_bf16((a_), (b_), (c_), 0, 0, 0))

#define QKV_PHASE(ABASE, P, STAGE_STMT, VM_STMT)                              \
  do {                                                                        \
    bf16x8 af0k0 = *(const bf16x8*)((ABASE) + (((P)*2)*16   + c16) * 64 + sw0);\
    bf16x8 af0k1 = *(const bf16x8*)((ABASE) + (((P)*2)*16   + c16) * 64 + sw1);\
    bf16x8 af1k0 = *(const bf16x8*)((ABASE) + (((P)*2+1)*16 + c16) * 64 + sw0);\
    bf16x8 af1k1 = *(const bf16x8*)((ABASE) + (((P)*2+1)*16 + c16) * 64 + sw1);\
    STAGE_STMT;                                                               \
    block_sync();                                                             \
    LGKM0();                                                                  \
    __builtin_amdgcn_s_setprio(1);                                            \
    _Pragma("unroll")                                                         \
    for (int nj = 0; nj < 4; nj++) {                                          \
      acc[(P)*2][nj]   = MF(af0k0, bf[nj][0], acc[(P)*2][nj]);                \
      acc[(P)*2][nj]   = MF(af0k1, bf[nj][1], acc[(P)*2][nj]);                \
      acc[(P)*2+1][nj] = MF(af1k0, bf[nj][0], acc[(P)*2+1][nj]);              \
      acc[(P)*2+1][nj] = MF(af1k1, bf[nj][1], acc[(P)*2+1][nj]);              \
    }                                                                         \
    __builtin_amdgcn_s_setprio(0);                                            \
    VM_STMT;                                                                  \
    block_sync();                                                             \
  } while (0)

template<int GRP>
__device__ __forceinline__ void qkv_core(
    const short* __restrict__ X, const short* __restrict__ W,
    const float* __restrict__ bias,
    short* __restrict__ Y, short* __restrict__ vT,
    short* lds, const int m_base, const int n_base)
{
    const int tid  = threadIdx.x;
    const int wv   = tid >> 6, lane = tid & 63;
    const int wm   = wv >> 2,  wn   = wv & 3;
    const int quad = lane >> 4, c16 = lane & 15;
    const int swz  = c16 & 7;
    const int sw0  = ((quad)     ^ swz) * 8;
    const int sw1  = ((quad + 4) ^ swz) * 8;

    auto stageA = [&](int k0, int d, int h) {
        short* dst = lds + d * 16384 + h * 8192;
#pragma unroll
        for (int g = 0; g < 2; g++) {
            const int idx = g * 512 + tid;
            const int row = idx >> 3, slot = idx & 7;
            gload16(X + (size_t)(m_base + h * 128 + row) * DD + k0
                      + ((slot ^ (row & 7)) * 8),
                    dst + row * 64 + slot * 8);
        }
    };
    auto stageB = [&](int k0, int d, int h) {
        short* dst = lds + 32768 + d * 16384 + h * 8192;
#pragma unroll
        for (int g = 0; g < 2; g++) {
            const int idx = g * 512 + tid;
            const int row = idx >> 3, slot = idx & 7;
            gload16(W + (size_t)(n_base + h * 128 + row) * DD + k0
                      + ((slot ^ (row & 7)) * 8),
                    dst + row * 64 + slot * 8);
        }
    };

    f32x4 acc[8][4];
#pragma unroll
    for (int i = 0; i < 8; i++)
#pragma unroll
        for (int j = 0; j < 4; j++) acc[i][j] = (f32x4){0.f, 0.f, 0.f, 0.f};

    stageA(0, 0, 0);  stageA(0, 0, 1);
    stageB(0, 0, 0);  stageB(0, 0, 1);
    stageB(64, 1, 0); stageB(64, 1, 1);
    VMCNT(4);
    block_sync();

    const short* Abuf0 = lds + wm * 8192;
    const short* Abuf1 = lds + 16384 + wm * 8192;
    const short* Bbuf0 = lds + 32768 + (wn >> 1) * 8192 + (wn & 1) * 4096;
    const short* Bbuf1 = lds + 49152 + (wn >> 1) * 8192 + (wn & 1) * 4096;

    bf16x8 bf[4][2];

    for (int it = 0; it < 8; ++it) {
        const int k1 = it * 128 + 64;
        const int k2 = it * 128 + 128;
        const int k3 = it * 128 + 192;
        const bool more = (it < 7);

#pragma unroll
        for (int nj = 0; nj < 4; nj++) {
            bf[nj][0] = *(const bf16x8*)(Bbuf0 + (nj * 16 + c16) * 64 + sw0);
            bf[nj][1] = *(const bf16x8*)(Bbuf0 + (nj * 16 + c16) * 64 + sw1);
        }
        QKV_PHASE(Abuf0, 0, stageA(k1, 1, 0), ((void)0));
        QKV_PHASE(Abuf0, 1, stageA(k1, 1, 1), ((void)0));
        QKV_PHASE(Abuf0, 2, if (more) stageB(k2, 0, 0), ((void)0));
        QKV_PHASE(Abuf0, 3, if (more) stageB(k2, 0, 1),
                  if (more) { VMCNT(4); } else { VMCNT(0); });

#pragma unroll
        for (int nj = 0; nj < 4; nj++) {
            bf[nj][0] = *(const bf16x8*)(Bbuf1 + (nj * 16 + c16) * 64 + sw0);
            bf[nj][1] = *(const bf16x8*)(Bbuf1 + (nj * 16 + c16) * 64 + sw1);
        }
        QKV_PHASE(Abuf1, 0, if (more) stageA(k2, 0, 0), ((void)0));
        QKV_PHASE(Abuf1, 1, if (more) stageA(k2, 0, 1), ((void)0));
        QKV_PHASE(Abuf1, 2, if (more) stageB(k3, 1, 0), ((void)0));
        QKV_PHASE(Abuf1, 3, if (more) stageB(k3, 1, 1),
                  if (more) { VMCNT(4); } else { VMCNT(0); });
    }

    if (GRP != 2) {
#pragma unroll
        for (int nj = 0; nj < 4; nj++) {
            const int col = n_base + wn * 64 + nj * 16 + c16;
            const float bc = bias[col];
#pragma unroll
            for (int mi = 0; mi < 8; mi++) {
                const int row = m_base + wm * 128 + mi * 16 + quad * 4;
#pragma unroll
                for (int r = 0; r < 4; r++)
                    Y[(size_t)(row + r) * DD + col] = f2bf(acc[mi][nj][r] + bc);
            }
        }
    } else {
#pragma unroll
        for (int nj = 0; nj < 4; nj++) {
#pragma unroll
            for (int r = 0; r < 4; r++) {
                const int drow = n_base + wn * 64 + nj * 16 + quad * 4 + r;
                const float bc = bias[drow];
#pragma unroll
                for (int mi = 0; mi < 8; mi++) {
                    const int mcol = m_base + wm * 128 + mi * 16 + c16;
                    vT[((size_t)(mcol >> 12) * DD + drow) * TT + (mcol & 4095)]
                        = f2bf(acc[mi][nj][r] + bc);
                }
            }
        }
    }
}

__global__ __launch_bounds__(512, 2) void qkv_gemm8(
    const short* __restrict__ X, const short* __restrict__ W3,
    const float* __restrict__ bq, const float* __restrict__ bk,
    const float* __restrict__ bv,
    short* __restrict__ q, short* __restrict__ k, short* __restrict__ vT)
{
    __shared__ __align__(16) short lds[65536];   // 128 KiB
    const int bid = blockIdx.x;                  // 768 blocks
    const int wg  = (bid & 7) * 96 + (bid >> 3); // bijective XCD swizzle
    const int mt  = wg & 63;
    const int cn  = wg >> 6;
    const int grp = cn >> 2;
    const int nt  = cn & 3;
    const int m_base = mt * 256;
    const int n_base = nt * 256;
    if (grp == 0)      qkv_core<0>(X, W3,              bq, q, nullptr, lds, m_base, n_base);
    else if (grp == 1) qkv_core<1>(X, W3 + DD * DD,    bk, k, nullptr, lds, m_base, n_base);
    else               qkv_core<2>(X, W3 + 2 * DD * DD, bv, nullptr, vT, lds, m_base, n_base);
}

// ============================================================
// K2 (round-5 = round-4 with the OOB fix): 512 thr / 8 waves.
// BUGFIX vs round 4: each wave owns 8 d-blocks x 4 jj = 32 output
// accumulators (16 rows x 512 cols); o_all was [16] indexed to 31
// (UB -> GPU fault).  Now o_all[32]; epilogue covers all 8 d-blocks.
//
// Wave roles: phase 1: wv = qt*2+kh ; phase 2: wv = qt*2+dh
// LDS map (shorts), total 78336 (156,672 B):
//   phase1 buf i @ i*20480 (i=0..2): Q[64][64]@+0, K[256][64]@+4096
//   P     @61440: [64][264]                (shorts 61440..78335)
//   smax  @49152 (128 f32), ssum @49408    (dead phase-1 buf2 space;
//          phase-2 V bufs end at short 49151)
//   phase2 V bufs [128][128] @ i*16384, i=0..2  (shorts 0..49151)
// ============================================================
__global__ __launch_bounds__(512, 2) void attn_fused(
    const short* __restrict__ Q,
    const short* __restrict__ Kb,
    const short* __restrict__ VT,    // [B,1024,4096]
    float* __restrict__ O)           // [16384,1024] fp32
{
    __shared__ short lds[78336];     // 156,672 B

    const int l   = blockIdx.x;
    const int xcd = l & 7;
    const int rr  = l >> 3;               // 0..31
    const int n   = xcd * 4 + (rr & 3);   // both qh of one (b,n) on same XCD
    const int qh  = (rr >> 2) & 1;
    const int b   = rr >> 3;

    const int tid  = threadIdx.x;         // 0..511
    const int wv   = tid >> 6, lane = tid & 63;
    const int quad = lane >> 4, c16 = lane & 15;
    const int qt   = wv >> 1;             // q-tile 0..3
    const int kh   = wv & 1;              // phase-1 k-half
    const int dh   = wv & 1;              // phase-2 d-half

    const int qrow   = b * TT + n * SS + qh * 64;
    const int krow   = b * TT + n * SS - SS;
    const int bstart = b * TT;

    // ---------------- phase 1: S = Q.K^T, BK=64, depth-2 ----------------
    f32x4 acc[8];
#pragma unroll
    for (int j = 0; j < 8; j++) acc[j] = (f32x4){0.f, 0.f, 0.f, 0.f};

    // stage: Q 1 gload/thr + K 4 gloads/thr = 5/thr.  T2: LDS dest linear,
    // global source column pre-swizzled, read side XORs the same key.
    auto stage1 = [&](int kk, int bi) {
        short* qb = lds + bi * 20480;
        short* kb = qb + 4096;
        const int k0 = kk * 64;
        {
            const int row = tid >> 3, slot = tid & 7;
            gload16(Q + (qrow + row) * DD + k0 + ((slot ^ (row & 7)) * 8),
                    qb + row * 64 + slot * 8);
        }
#pragma unroll
        for (int g = 0; g < 4; g++) {
            const int idx = g * 512 + tid;
            const int row = idx >> 3, slot = idx & 7;
            int grow = krow + row;
            if (grow < bstart) grow = bstart;   // n==0 pad rows (masked below)
            gload16(Kb + grow * DD + k0 + ((slot ^ (row & 7)) * 8),
                    kb + row * 64 + slot * 8);
        }
    };

    const int sw7 = c16 & 7;   // read-side swizzle key (rows are x*16+c16)

    stage1(0, 0);
    stage1(1, 1);
    for (int kk = 0; kk < 16; kk++) {
        if (kk < 15) { VMCNT(5); } else { VMCNT(0); }   // own stage(kk) landed
        block_sync();                                    // everyone's landed
        if (kk < 14) stage1(kk + 2, (kk + 2) % 3);       // 2 tiles in flight
        const short* qb = lds + (kk % 3) * 20480;
        const short* kb = qb + 4096;
        __builtin_amdgcn_s_setprio(1);
#pragma unroll
        for (int ks = 0; ks < 2; ks++) {
            const int slot = ((ks * 4 + quad) ^ sw7) * 8;
            bf16x8 a = *(const bf16x8*)(qb + (qt * 16 + c16) * 64 + slot);
#pragma unroll
            for (int j = 0; j < 8; j++) {
                bf16x8 bf = *(const bf16x8*)(kb + (kh * 128 + j * 16 + c16) * 64 + slot);
                acc[j] = __builtin_amdgcn_mfma_f32_16x16x32_bf16(a, bf, acc[j], 0, 0, 0);
            }
        }
        __builtin_amdgcn_s_setprio(0);
    }

    block_sync();   // all waves done reading phase-1 bufs (region reused by V)

    // ---- phase-2 prologue issued BEFORE softmax: V loads fly under it ----
    const int tbase = n * SS - SS;
    auto stage2 = [&](int s, int bi) {
        short* vb = lds + bi * 16384;
        const int d0  = (s >> 1) * 128;
        const int khv = (s & 1) * 128;
#pragma unroll
        for (int g = 0; g < 4; g++) {
            const int idx = g * 512 + tid;
            const int row = idx >> 4, slot = idx & 15;   // d-local row, 16B slot
            int t = tbase + khv + ((slot ^ (row & 15)) * 8);
            if (t < 0) t = 0;                            // n==0 pad keys: P==0
            gload16(VT + (size_t)(b * DD + d0 + row) * TT + t,
                    vb + row * 128 + slot * 8);
        }
    };
    stage2(0, 0);
    stage2(1, 1);

    // ---------------- softmax: cross-wave over k-halves ----------------
    short* Pb   = lds + 61440;                    // [64][264]
    float* smax = (float*)(lds + 49152);          // [8 waves][16 rows]
    float* ssum = (float*)(lds + 49408);
    const float scale = 0.03125f;   // 1/sqrt(1024)
    float mx4[4], sums[4];

#pragma unroll
    for (int r = 0; r < 4; r++) {                 // pass A: mask + local max
        const int q_idx = qh * 64 + qt * 16 + quad * 4 + r;   // 0..127
        float mx = -3.0e38f;
#pragma unroll
        for (int j = 0; j < 8; j++) {
            const int k_idx = kh * 128 + j * 16 + c16;         // 0..255
            const int rel = k_idx - SS - q_idx;
            const bool valid = (rel <= 0) & (rel > -SS) & ((n > 0) | (k_idx >= SS));
            const float sv = valid ? acc[j][r] * scale : -3.0e38f;
            acc[j][r] = sv;
            mx = fmaxf(mx, sv);
        }
#pragma unroll
        for (int o = 1; o < 16; o <<= 1) mx = fmaxf(mx, __shfl_xor(mx, o));
        mx4[r] = mx;
        if (c16 == 0) smax[(qt * 2 + kh) * 16 + quad * 4 + r] = mx;
    }
    LGKM0(); block_sync();

#pragma unroll
    for (int r = 0; r < 4; r++) {                 // pass B: exp + local sum
        const float M = fmaxf(mx4[r], smax[(qt * 2 + (kh ^ 1)) * 16 + quad * 4 + r]);
        float sm = 0.f;
#pragma unroll
        for (int j = 0; j < 8; j++) {
            const float p = __expf(acc[j][r] - M);
            acc[j][r] = p;
            sm += p;
        }
#pragma unroll
        for (int o = 1; o < 16; o <<= 1) sm += __shfl_xor(sm, o);
        sums[r] = sm;
        if (c16 == 0) ssum[(qt * 2 + kh) * 16 + quad * 4 + r] = sm;
    }
    LGKM0(); block_sync();

#pragma unroll
    for (int r = 0; r < 4; r++) {                 // pass C: normalize -> P
        const float inv = 1.0f / (sums[r] + ssum[(qt * 2 + (kh ^ 1)) * 16 + quad * 4 + r]);
#pragma unroll
        for (int j = 0; j < 8; j++)
            Pb[(qt * 16 + quad * 4 + r) * 264 + kh * 128 + j * 16 + c16] = f2bf(acc[j][r] * inv);
    }
    LGKM0();    // P writes retired before the next barrier releases readers

    // ---------------- phase 2: O = P.V, depth-2, O in registers ----------------
    f32x4 o_all[32];                 // 8 d-blocks x 4 jj  (BUGFIX: was [16])
#pragma unroll
    for (int j = 0; j < 32; j++) o_all[j] = (f32x4){0.f, 0.f, 0.f, 0.f};

#pragma unroll
    for (int s = 0; s < 16; s++) {
        if (s < 15) { VMCNT(4); } else { VMCNT(0); }   // own stage(s) landed
        block_sync();                                   // all waves' landed; P visible (s=0)
        if (s < 14) stage2(s + 2, (s + 2) % 3);
        const short* vb = lds + (s % 3) * 16384;
        const int khP = (s & 1) * 128;
        const int od  = (s >> 1) * 4;                   // 0..28, static after unroll
        __builtin_amdgcn_s_setprio(1);
#pragma unroll
        for (int kc = 0; kc < 4; kc++) {
            bf16x8 a = *(const bf16x8*)(Pb + (qt * 16 + c16) * 264 + khP + kc * 32 + quad * 8);
#pragma unroll
            for (int jj = 0; jj < 4; jj++) {
                bf16x8 bvf = *(const bf16x8*)(vb + (dh * 64 + jj * 16 + c16) * 128
                                              + (((kc * 4 + quad) ^ c16) * 8));
                o_all[od + jj] = __builtin_amdgcn_mfma_f32_16x16x32_bf16(a, bvf, o_all[od + jj], 0, 0, 0);
            }
        }
        __builtin_amdgcn_s_setprio(0);
    }

    // ---- epilogue: coalesced O stores, once (all 8 d-blocks) ----
#pragma unroll
    for (int d0i = 0; d0i < 8; d0i++)
#pragma unroll
        for (int jj = 0; jj < 4; jj++)
#pragma unroll
            for (int r = 0; r < 4; r++)
                O[(size_t)(qrow + qt * 16 + quad * 4 + r) * DD
                  + d0i * 128 + dh * 64 + jj * 16 + c16] = o_all[d0i * 4 + jj][r];
}

// ============================================================
extern "C" void kernel_launch(void* const* d_in, const int* in_sizes, int n_in,
                              void* d_out, int out_size, void* d_ws, size_t ws_size,
                              hipStream_t stream) {
    const float* x  = (const float*)d_in[0];
    const float* Wq = (const float*)d_in[1];
    const float* bq = (const float*)d_in[2];
    const float* Wk = (const float*)d_in[3];
    const float* bk = (const float*)d_in[4];
    const float* Wv = (const float*)d_in[5];
    const float* bv = (const float*)d_in[6];
    float* out = (float*)d_out;

    char* ws = (char*)d_ws;
    const size_t SZ = (size_t)MM * DD * 2;     // 33,554,432 B
    short* q   = (short*)(ws);
    short* k   = (short*)(ws + SZ);
    short* vT  = (short*)(ws + 2 * SZ);
    short* xb  = (short*)(ws + 3 * SZ);
    short* w3b = (short*)(ws + 4 * SZ);        // [3][1024][1024] contiguous

    dim3 blk(256);
    cast_f32_bf16<<<MM * DD / 1024, blk, 0, stream>>>(x, xb);
    cast_w3<<<dim3(DD * DD / 1024, 3), blk, 0, stream>>>(Wq, Wk, Wv, w3b);

    qkv_gemm8<<<768, 512, 0, stream>>>(xb, w3b, bq, bk, bv, q, k, vT);

    attn_fused<<<256, 512, 0, stream>>>(q, k, vT, out);
}

// Round 6
// 272.303 us; speedup vs baseline: 1.1784x; 1.0855x over previous
//
#include <hip/hip_runtime.h>
#include <hip/hip_bf16.h>

// ---- problem constants (B=4, T=4096, D=1024, SPAN=128) ----
#define BB 4
#define TT 4096
#define DD 1024
#define SS 128
#define MM (BB*TT)       // 16384 rows

typedef __attribute__((ext_vector_type(8))) short bf16x8;
typedef __attribute__((ext_vector_type(4))) short s16x4;
typedef __attribute__((ext_vector_type(4))) float f32x4;

// counted vmem wait: lets N newest vmem ops stay in flight (in-order retire)
#define VMCNT(N) asm volatile("s_waitcnt vmcnt(" #N ")" ::: "memory")
#define LGKM0()  asm volatile("s_waitcnt lgkmcnt(0)" ::: "memory")

__device__ __forceinline__ void block_sync() {
    asm volatile("" ::: "memory");
    __builtin_amdgcn_s_barrier();
    asm volatile("" ::: "memory");
}

__device__ __forceinline__ short f2bf(float f) {
    union { float f; unsigned u; } cv; cv.f = f;
    unsigned u = cv.u;
    u += 0x7fffu + ((u >> 16) & 1u);   // RNE
    return (short)(u >> 16);
}

// direct global->LDS DMA, 16B/lane. Contract: LDS dest = wave-uniform
// base + lane*16 (verified for every call site below).
__device__ __forceinline__ void gload16(const short* g, short* l) {
    __builtin_amdgcn_global_load_lds(
        (const __attribute__((address_space(1))) void*)g,
        (__attribute__((address_space(3))) void*)l, 16, 0, 0);
}

// ============================================================
// K0a: x fp32 -> bf16
// ============================================================
__global__ __launch_bounds__(256) void cast_f32_bf16(
    const float* __restrict__ src, short* __restrict__ dst)
{
    const int i = (blockIdx.x * 256 + threadIdx.x) * 4;
    const float4 v = *(const float4*)(src + i);
    s16x4 o;
    o.x = f2bf(v.x); o.y = f2bf(v.y); o.z = f2bf(v.z); o.w = f2bf(v.w);
    *(s16x4*)(dst + i) = o;
}

// K0b: three weight matrices, one launch (dst contiguous [3][1024][1024])
__global__ __launch_bounds__(256) void cast_w3(
    const float* __restrict__ a, const float* __restrict__ b,
    const float* __restrict__ c, short* __restrict__ dst)
{
    const float* src = (blockIdx.y == 0) ? a : (blockIdx.y == 1) ? b : c;
    short* d = dst + (size_t)blockIdx.y * DD * DD;
    const int i = (blockIdx.x * 256 + threadIdx.x) * 4;
    const float4 v = *(const float4*)(src + i);
    s16x4 o;
    o.x = f2bf(v.x); o.y = f2bf(v.y); o.z = f2bf(v.z); o.w = f2bf(v.w);
    *(s16x4*)(d + i) = o;
}

// ============================================================
// K1: 256x256 8-phase GEMM.  Round-6 change: XCD-rectangular decode —
// XCD x owns mt in [8x, 8x+8) x all 12 cn, so the per-XCD X working
// set is 4 MB (L2-resident) instead of ~32 MB.  Core unchanged.
// ============================================================

#define MF(a_, b_, c_) ((GRP == 2)                                            \
    ? __builtin_amdgcn_mfma_f32_16x16x32_bf16((b_), (a_), (c_), 0, 0, 0)      \
    : __builtin_amdgcn_mfma_f32_16x16x32_bf16((a_), (b_), (c_), 0, 0, 0))

#define QKV_PHASE(ABASE, P, STAGE_STMT, VM_STMT)                              \
  do {                                                                        \
    bf16x8 af0k0 = *(const bf16x8*)((ABASE) + (((P)*2)*16   + c16) * 64 + sw0);\
    bf16x8 af0k1 = *(const bf16x8*)((ABASE) + (((P)*2)*16   + c16) * 64 + sw1);\
    bf16x8 af1k0 = *(const bf16x8*)((ABASE) + (((P)*2+1)*16 + c16) * 64 + sw0);\
    bf16x8 af1k1 = *(const bf16x8*)((ABASE) + (((P)*2+1)*16 + c16) * 64 + sw1);\
    STAGE_STMT;                                                               \
    block_sync();                                                             \
    LGKM0();                                                                  \
    __builtin_amdgcn_s_setprio(1);                                            \
    _Pragma("unroll")                                                         \
    for (int nj = 0; nj < 4; nj++) {                                          \
      acc[(P)*2][nj]   = MF(af0k0, bf[nj][0], acc[(P)*2][nj]);                \
      acc[(P)*2][nj]   = MF(af0k1, bf[nj][1], acc[(P)*2][nj]);                \
      acc[(P)*2+1][nj] = MF(af1k0, bf[nj][0], acc[(P)*2+1][nj]);              \
      acc[(P)*2+1][nj] = MF(af1k1, bf[nj][1], acc[(P)*2+1][nj]);              \
    }                                                                         \
    __builtin_amdgcn_s_setprio(0);                                            \
    VM_STMT;                                                                  \
    block_sync();                                                             \
  } while (0)

template<int GRP>
__device__ __forceinline__ void qkv_core(
    const short* __restrict__ X, const short* __restrict__ W,
    const float* __restrict__ bias,
    short* __restrict__ Y, short* __restrict__ vT,
    short* lds, const int m_base, const int n_base)
{
    const int tid  = threadIdx.x;
    const int wv   = tid >> 6, lane = tid & 63;
    const int wm   = wv >> 2,  wn   = wv & 3;
    const int quad = lane >> 4, c16 = lane & 15;
    const int swz  = c16 & 7;
    const int sw0  = ((quad)     ^ swz) * 8;
    const int sw1  = ((quad + 4) ^ swz) * 8;

    auto stageA = [&](int k0, int d, int h) {
        short* dst = lds + d * 16384 + h * 8192;
#pragma unroll
        for (int g = 0; g < 2; g++) {
            const int idx = g * 512 + tid;
            const int row = idx >> 3, slot = idx & 7;
            gload16(X + (size_t)(m_base + h * 128 + row) * DD + k0
                      + ((slot ^ (row & 7)) * 8),
                    dst + row * 64 + slot * 8);
        }
    };
    auto stageB = [&](int k0, int d, int h) {
        short* dst = lds + 32768 + d * 16384 + h * 8192;
#pragma unroll
        for (int g = 0; g < 2; g++) {
            const int idx = g * 512 + tid;
            const int row = idx >> 3, slot = idx & 7;
            gload16(W + (size_t)(n_base + h * 128 + row) * DD + k0
                      + ((slot ^ (row & 7)) * 8),
                    dst + row * 64 + slot * 8);
        }
    };

    f32x4 acc[8][4];
#pragma unroll
    for (int i = 0; i < 8; i++)
#pragma unroll
        for (int j = 0; j < 4; j++) acc[i][j] = (f32x4){0.f, 0.f, 0.f, 0.f};

    stageA(0, 0, 0);  stageA(0, 0, 1);
    stageB(0, 0, 0);  stageB(0, 0, 1);
    stageB(64, 1, 0); stageB(64, 1, 1);
    VMCNT(4);
    block_sync();

    const short* Abuf0 = lds + wm * 8192;
    const short* Abuf1 = lds + 16384 + wm * 8192;
    const short* Bbuf0 = lds + 32768 + (wn >> 1) * 8192 + (wn & 1) * 4096;
    const short* Bbuf1 = lds + 49152 + (wn >> 1) * 8192 + (wn & 1) * 4096;

    bf16x8 bf[4][2];

    for (int it = 0; it < 8; ++it) {
        const int k1 = it * 128 + 64;
        const int k2 = it * 128 + 128;
        const int k3 = it * 128 + 192;
        const bool more = (it < 7);

#pragma unroll
        for (int nj = 0; nj < 4; nj++) {
            bf[nj][0] = *(const bf16x8*)(Bbuf0 + (nj * 16 + c16) * 64 + sw0);
            bf[nj][1] = *(const bf16x8*)(Bbuf0 + (nj * 16 + c16) * 64 + sw1);
        }
        QKV_PHASE(Abuf0, 0, stageA(k1, 1, 0), ((void)0));
        QKV_PHASE(Abuf0, 1, stageA(k1, 1, 1), ((void)0));
        QKV_PHASE(Abuf0, 2, if (more) stageB(k2, 0, 0), ((void)0));
        QKV_PHASE(Abuf0, 3, if (more) stageB(k2, 0, 1),
                  if (more) { VMCNT(4); } else { VMCNT(0); });

#pragma unroll
        for (int nj = 0; nj < 4; nj++) {
            bf[nj][0] = *(const bf16x8*)(Bbuf1 + (nj * 16 + c16) * 64 + sw0);
            bf[nj][1] = *(const bf16x8*)(Bbuf1 + (nj * 16 + c16) * 64 + sw1);
        }
        QKV_PHASE(Abuf1, 0, if (more) stageA(k2, 0, 0), ((void)0));
        QKV_PHASE(Abuf1, 1, if (more) stageA(k2, 0, 1), ((void)0));
        QKV_PHASE(Abuf1, 2, if (more) stageB(k3, 1, 0), ((void)0));
        QKV_PHASE(Abuf1, 3, if (more) stageB(k3, 1, 1),
                  if (more) { VMCNT(4); } else { VMCNT(0); });
    }

    if (GRP != 2) {
#pragma unroll
        for (int nj = 0; nj < 4; nj++) {
            const int col = n_base + wn * 64 + nj * 16 + c16;
            const float bc = bias[col];
#pragma unroll
            for (int mi = 0; mi < 8; mi++) {
                const int row = m_base + wm * 128 + mi * 16 + quad * 4;
#pragma unroll
                for (int r = 0; r < 4; r++)
                    Y[(size_t)(row + r) * DD + col] = f2bf(acc[mi][nj][r] + bc);
            }
        }
    } else {
#pragma unroll
        for (int nj = 0; nj < 4; nj++) {
#pragma unroll
            for (int r = 0; r < 4; r++) {
                const int drow = n_base + wn * 64 + nj * 16 + quad * 4 + r;
                const float bc = bias[drow];
#pragma unroll
                for (int mi = 0; mi < 8; mi++) {
                    const int mcol = m_base + wm * 128 + mi * 16 + c16;
                    vT[((size_t)(mcol >> 12) * DD + drow) * TT + (mcol & 4095)]
                        = f2bf(acc[mi][nj][r] + bc);
                }
            }
        }
    }
}

__global__ __launch_bounds__(512, 2) void qkv_gemm8(
    const short* __restrict__ X, const short* __restrict__ W3,
    const float* __restrict__ bq, const float* __restrict__ bk,
    const float* __restrict__ bv,
    short* __restrict__ q, short* __restrict__ k, short* __restrict__ vT)
{
    __shared__ __align__(16) short lds[65536];   // 128 KiB
    const int bid = blockIdx.x;                  // 768 blocks
    // XCD-rectangular decode: XCD x = bid&7 owns mt in [8x, 8x+8) x cn 0..11
    // (per-XCD X working set = 8 panels = 4 MB -> L2-resident).  Bijective.
    const int x   = bid & 7;
    const int j   = bid >> 3;                    // 0..95
    const int mt  = x * 8 + (j & 7);             // 0..63
    const int cn  = j >> 3;                      // 0..11
    const int grp = cn >> 2;
    const int nt  = cn & 3;
    const int m_base = mt * 256;
    const int n_base = nt * 256;
    if (grp == 0)      qkv_core<0>(X, W3,              bq, q, nullptr, lds, m_base, n_base);
    else if (grp == 1) qkv_core<1>(X, W3 + DD * DD,    bk, k, nullptr, lds, m_base, n_base);
    else               qkv_core<2>(X, W3 + 2 * DD * DD, bv, nullptr, vT, lds, m_base, n_base);
}

// ============================================================
// K2 (round-6): 192-key window.  A 64-q-row tile (qh half) only needs
// keys [n*S - S + qh*64, n*S + qh*64 + 64) = 192 keys, not the full
// 256-window: K/V fetch, QK^T and PV MFMA, and LDS traffic all -25%,
// uniformly across waves (window shift qh*64 is block-uniform).
// Mask: kbase = n*S - S + qh*64; rel = k_local - 128 - ql (ql 0..63);
// pad (n==0): valid iff k_local >= 128 - qh*64.
//
// Wave roles: phase 1: wv = qt*2+kh (kh = 96-key half);
//             phase 2: wv = qt*2+dh (dh = 128-d half of a 256-d step)
// Phase 2: 12 steps of V[256 d][64 t] (16 MFMA/wave/step); total
// barriers 16+12 = 28 (was 32).
//
// LDS map (shorts), total 74240 (148,480 B):
//   phase1 buf i @ i*16384 (i=0..2): Q[64][64]@+0, K[192][64]@+4096
//   smax @49152 (128 f32), ssum @49408 (outside all bufs)
//   phase2 V bufs [256][64] @ i*16384, i=0..2 (shorts 0..49151, reuse)
//   P    @61440: [64][200]  (61440..74239)
// vmcnt ledger: stage1 = 4 loads/thr (1Q+3K) -> steady VMCNT(4);
//   stage2 = 4 loads/thr -> steady VMCNT(4); depth-2 both phases.
// ============================================================
__global__ __launch_bounds__(512, 2) void attn_fused(
    const short* __restrict__ Q,
    const short* __restrict__ Kb,
    const short* __restrict__ VT,    // [B,1024,4096]
    float* __restrict__ O)           // [16384,1024] fp32
{
    __shared__ short lds[74240];     // 148,480 B

    const int l   = blockIdx.x;
    const int xcd = l & 7;
    const int rr  = l >> 3;               // 0..31
    const int n   = xcd * 4 + (rr & 3);   // both qh of one (b,n) on same XCD
    const int qh  = (rr >> 2) & 1;
    const int b   = rr >> 3;

    const int tid  = threadIdx.x;         // 0..511
    const int wv   = tid >> 6, lane = tid & 63;
    const int quad = lane >> 4, c16 = lane & 15;
    const int qt   = wv >> 1;             // q-tile 0..3
    const int kh   = wv & 1;              // phase-1 96-key half
    const int dh   = wv & 1;              // phase-2 d-half

    const int qrow   = b * TT + n * SS + qh * 64;          // first q row
    const int kbase  = b * TT + n * SS - SS + qh * 64;     // key-window row 0
    const int bstart = b * TT;

    // ---------------- phase 1: S = Q.K^T over 192 keys, BK=64, depth-2 ----
    f32x4 acc[6];
#pragma unroll
    for (int j = 0; j < 6; j++) acc[j] = (f32x4){0.f, 0.f, 0.f, 0.f};

    // stage: Q 1 gload/thr + K 3 gloads/thr = 4/thr.  T2: LDS dest linear,
    // global source column pre-swizzled, read side XORs the same key.
    auto stage1 = [&](int kk, int bi) {
        short* qb = lds + bi * 16384;
        short* kb = qb + 4096;
        const int k0 = kk * 64;
        {
            const int row = tid >> 3, slot = tid & 7;
            gload16(Q + (qrow + row) * DD + k0 + ((slot ^ (row & 7)) * 8),
                    qb + row * 64 + slot * 8);
        }
#pragma unroll
        for (int g = 0; g < 3; g++) {
            const int idx = g * 512 + tid;
            const int row = idx >> 3, slot = idx & 7;   // row 0..191
            int grow = kbase + row;
            if (grow < bstart) grow = bstart;   // n==0 pad rows (masked below)
            gload16(Kb + grow * DD + k0 + ((slot ^ (row & 7)) * 8),
                    kb + row * 64 + slot * 8);
        }
    };

    const int sw7 = c16 & 7;   // read-side swizzle key (rows are x*16+c16)

    stage1(0, 0);
    stage1(1, 1);
    for (int kk = 0; kk < 16; kk++) {
        if (kk < 15) { VMCNT(4); } else { VMCNT(0); }   // own stage(kk) landed
        block_sync();                                    // everyone's landed
        if (kk < 14) stage1(kk + 2, (kk + 2) % 3);       // 2 tiles in flight
        const short* qb = lds + (kk % 3) * 16384;
        const short* kb = qb + 4096;
        __builtin_amdgcn_s_setprio(1);
#pragma unroll
        for (int ks = 0; ks < 2; ks++) {
            const int slot = ((ks * 4 + quad) ^ sw7) * 8;
            bf16x8 a = *(const bf16x8*)(qb + (qt * 16 + c16) * 64 + slot);
#pragma unroll
            for (int j = 0; j < 6; j++) {
                bf16x8 bf = *(const bf16x8*)(kb + (kh * 96 + j * 16 + c16) * 64 + slot);
                acc[j] = __builtin_amdgcn_mfma_f32_16x16x32_bf16(a, bf, acc[j], 0, 0, 0);
            }
        }
        __builtin_amdgcn_s_setprio(0);
    }

    block_sync();   // all waves done reading phase-1 bufs (region reused by V)

    // ---- phase-2 prologue issued BEFORE softmax: V loads fly under it ----
    const int tb2 = n * SS - SS + qh * 64;   // abs t of kv-window col 0
    auto stage2 = [&](int s, int bi) {
        short* vb = lds + bi * 16384;
        const int d0  = (s / 3) * 256;
        const int kv0 = (s % 3) * 64;
#pragma unroll
        for (int g = 0; g < 4; g++) {
            const int idx = g * 512 + tid;
            const int row = idx >> 3, slot = idx & 7;   // d-local row 0..255
            int t = tb2 + kv0 + ((slot ^ (row & 7)) * 8);
            if (t < 0) t = 0;                            // n==0 pad keys: P==0
            gload16(VT + (size_t)(b * DD + d0 + row) * TT + t,
                    vb + row * 64 + slot * 8);
        }
    };
    stage2(0, 0);
    stage2(1, 1);

    // ---------------- softmax: cross-wave over 96-key halves ----------------
    short* Pb   = lds + 61440;                    // [64][200]
    float* smax = (float*)(lds + 49152);          // [8 waves][16 rows]
    float* ssum = (float*)(lds + 49408);
    const float scale = 0.03125f;   // 1/sqrt(1024)
    const int   padk  = (n > 0) ? 0 : (SS - qh * 64);   // valid: k_local >= padk
    float mx4[4], sums[4];

#pragma unroll
    for (int r = 0; r < 4; r++) {                 // pass A: mask + local max
        const int ql = qt * 16 + quad * 4 + r;    // local q row 0..63
        float mx = -3.0e38f;
#pragma unroll
        for (int j = 0; j < 6; j++) {
            const int k_local = kh * 96 + j * 16 + c16;        // 0..191
            const int rel = k_local - SS - ql;
            const bool valid = (rel <= 0) & (rel > -SS) & (k_local >= padk);
            const float sv = valid ? acc[j][r] * scale : -3.0e38f;
            acc[j][r] = sv;
            mx = fmaxf(mx, sv);
        }
#pragma unroll
        for (int o = 1; o < 16; o <<= 1) mx = fmaxf(mx, __shfl_xor(mx, o));
        mx4[r] = mx;
        if (c16 == 0) smax[(qt * 2 + kh) * 16 + quad * 4 + r] = mx;
    }
    LGKM0(); block_sync();

#pragma unroll
    for (int r = 0; r < 4; r++) {                 // pass B: exp + local sum
        const float M = fmaxf(mx4[r], smax[(qt * 2 + (kh ^ 1)) * 16 + quad * 4 + r]);
        float sm = 0.f;
#pragma unroll
        for (int j = 0; j < 6; j++) {
            const float p = __expf(acc[j][r] - M);
            acc[j][r] = p;
            sm += p;
        }
#pragma unroll
        for (int o = 1; o < 16; o <<= 1) sm += __shfl_xor(sm, o);
        sums[r] = sm;
        if (c16 == 0) ssum[(qt * 2 + kh) * 16 + quad * 4 + r] = sm;
    }
    LGKM0(); block_sync();

#pragma unroll
    for (int r = 0; r < 4; r++) {                 // pass C: normalize -> P
        const float inv = 1.0f / (sums[r] + ssum[(qt * 2 + (kh ^ 1)) * 16 + quad * 4 + r]);
#pragma unroll
        for (int j = 0; j < 6; j++)
            Pb[(qt * 16 + quad * 4 + r) * 200 + kh * 96 + j * 16 + c16] = f2bf(acc[j][r] * inv);
    }
    LGKM0();    // P writes retired before the next barrier releases readers

    // -------- phase 2: O = P.V, 12 steps of V[256 d][64 t], depth-2 --------
    f32x4 o_all[32];                 // 4 d-groups x 8 jj
#pragma unroll
    for (int j = 0; j < 32; j++) o_all[j] = (f32x4){0.f, 0.f, 0.f, 0.f};

#pragma unroll
    for (int s = 0; s < 12; s++) {
        if (s < 11) { VMCNT(4); } else { VMCNT(0); }   // own stage(s) landed
        block_sync();                                   // all landed; P visible (s=0)
        if (s < 10) stage2(s + 2, (s + 2) % 3);
        const short* vb = lds + (s % 3) * 16384;
        const int kv0 = (s % 3) * 64;
        const int od  = (s / 3) * 8;                    // 0..24, static after unroll
        __builtin_amdgcn_s_setprio(1);
#pragma unroll
        for (int kc = 0; kc < 2; kc++) {
            bf16x8 a = *(const bf16x8*)(Pb + (qt * 16 + c16) * 200 + kv0 + kc * 32 + quad * 8);
#pragma unroll
            for (int jj = 0; jj < 8; jj++) {
                bf16x8 bvf = *(const bf16x8*)(vb + (dh * 128 + jj * 16 + c16) * 64
                                              + (((kc * 4 + quad) ^ sw7) * 8));
                o_all[od + jj] = __builtin_amdgcn_mfma_f32_16x16x32_bf16(a, bvf, o_all[od + jj], 0, 0, 0);
            }
        }
        __builtin_amdgcn_s_setprio(0);
    }

    // ---- epilogue: coalesced O stores, once (4 d-groups x 8 jj) ----
#pragma unroll
    for (int g8 = 0; g8 < 4; g8++)
#pragma unroll
        for (int jj = 0; jj < 8; jj++)
#pragma unroll
            for (int r = 0; r < 4; r++)
                O[(size_t)(qrow + qt * 16 + quad * 4 + r) * DD
                  + g8 * 256 + dh * 128 + jj * 16 + c16] = o_all[g8 * 8 + jj][r];
}

// ============================================================
extern "C" void kernel_launch(void* const* d_in, const int* in_sizes, int n_in,
                              void* d_out, int out_size, void* d_ws, size_t ws_size,
                              hipStream_t stream) {
    const float* x  = (const float*)d_in[0];
    const float* Wq = (const float*)d_in[1];
    const float* bq = (const float*)d_in[2];
    const float* Wk = (const float*)d_in[3];
    const float* bk = (const float*)d_in[4];
    const float* Wv = (const float*)d_in[5];
    const float* bv = (const float*)d_in[6];
    float* out = (float*)d_out;

    char* ws = (char*)d_ws;
    const size_t SZ = (size_t)MM * DD * 2;     // 33,554,432 B
    short* q   = (short*)(ws);
    short* k   = (short*)(ws + SZ);
    short* vT  = (short*)(ws + 2 * SZ);
    short* xb  = (short*)(ws + 3 * SZ);
    short* w3b = (short*)(ws + 4 * SZ);        // [3][1024][1024] contiguous

    dim3 blk(256);
    cast_f32_bf16<<<MM * DD / 1024, blk, 0, stream>>>(x, xb);
    cast_w3<<<dim3(DD * DD / 1024, 3), blk, 0, stream>>>(Wq, Wk, Wv, w3b);

    qkv_gemm8<<<768, 512, 0, stream>>>(xb, w3b, bq, bk, bv, q, k, vT);

    attn_fused<<<256, 512, 0, stream>>>(q, k, vT, out);
}